// Round 1
// baseline (481.198 us; speedup 1.0000x reference)
//
#include <hip/hip_runtime.h>
#include <hip/hip_bf16.h>
#include <math.h>

#define B_ 8
#define T_ 256
#define LQ_ 20
#define LC_ 10
#define DIM_ 128
#define N_ 257            // T+1
#define NN_ (B_*N_)       // 2056

// ---------------- Kernel A: node features (video + query branches) ----------
__global__ __launch_bounds__(256) void k_nodes(
    const int* __restrict__ word_ids, const int* __restrict__ char_ids,
    const float* __restrict__ video,
    const float* __restrict__ v_mask, const float* __restrict__ q_mask,
    const float* __restrict__ word_emb, const float* __restrict__ char_emb,
    const float* __restrict__ W_embed, const float* __restrict__ b_embed,
    const float* __restrict__ W_vproj, const float* __restrict__ b_vproj,
    const float* __restrict__ W_enc, const float* __restrict__ b_enc,
    float* __restrict__ xf)
{
  int blk = blockIdx.x;
  int tid = threadIdx.x;
  __shared__ float vlds[8 * 1024];       // 32 KB: 8 video rows
  __shared__ float hlds[8][128];
  __shared__ float emb[352];
  __shared__ float hq[128];

  if (blk < 256) {
    // ---- video branch: rows r0..r0+7 ----
    int r0 = blk * 8;
    const float4* src = reinterpret_cast<const float4*>(video + r0 * 1024);
    float4* dst4 = reinterpret_cast<float4*>(vlds);
    for (int idx = tid; idx < 2048; idx += 256) dst4[idx] = src[idx];
    __syncthreads();
    int j = tid & 127, g = tid >> 7;
    float acc[4];
    #pragma unroll
    for (int r = 0; r < 4; ++r) acc[r] = b_vproj[j];
    #pragma unroll 8
    for (int k = 0; k < 1024; ++k) {
      float w = W_vproj[k * 128 + j];
      #pragma unroll
      for (int r = 0; r < 4; ++r) acc[r] += vlds[(g * 4 + r) * 1024 + k] * w;
    }
    #pragma unroll
    for (int r = 0; r < 4; ++r) hlds[g * 4 + r][j] = acc[r];
    __syncthreads();
    float out[4];
    #pragma unroll
    for (int r = 0; r < 4; ++r) out[r] = b_enc[j];
    #pragma unroll 4
    for (int k = 0; k < 128; ++k) {
      float w = W_enc[k * 128 + j];
      #pragma unroll
      for (int r = 0; r < 4; ++r) out[r] += hlds[g * 4 + r][k] * w;
    }
    #pragma unroll
    for (int r = 0; r < 4; ++r) {
      int vr = r0 + g * 4 + r;
      int bi = vr >> 8, t = vr & 255;
      float e = fmaxf(out[r], 0.f) * v_mask[vr];
      xf[(bi * 257 + 1 + t) * 128 + j] = e;
    }
  } else {
    // ---- query branch: one block per batch ----
    int b = blk - 256;
    int j = tid & 127;
    float qacc = 0.f;
    for (int lq = 0; lq < LQ_; ++lq) {
      int wid = word_ids[b * LQ_ + lq];
      for (int m = tid; m < 300; m += 256) emb[m] = word_emb[wid * 300 + m];
      for (int c = tid; c < 50; c += 256) {
        float s = 0.f;
        #pragma unroll
        for (int l = 0; l < 10; ++l) {
          int cid = char_ids[(b * LQ_ + lq) * 10 + l];
          s += char_emb[cid * 50 + c];
        }
        emb[300 + c] = s * 0.1f;
      }
      __syncthreads();
      if (tid < 128) {
        float h = b_embed[j];
        for (int m = 0; m < 350; ++m) h += emb[m] * W_embed[m * 128 + j];
        hq[j] = h;
      }
      __syncthreads();
      if (tid < 128) {
        float e = b_enc[j];
        #pragma unroll 4
        for (int k = 0; k < 128; ++k) e += hq[k] * W_enc[k * 128 + j];
        e = fmaxf(e, 0.f) * q_mask[b * LQ_ + lq];
        qacc += e;
      }
      __syncthreads();
    }
    if (tid < 128) xf[(b * 257) * 128 + j] = qacc * (1.f / LQ_);
  }
}

// ---------------- Kernel B: q/k/v/skip projections ---------------------------
__global__ __launch_bounds__(256) void k_proj(
    const float* __restrict__ xf,
    const float* __restrict__ Wq, const float* __restrict__ bq,
    const float* __restrict__ Wk, const float* __restrict__ bk,
    const float* __restrict__ Wv, const float* __restrict__ bv,
    const float* __restrict__ Ws, const float* __restrict__ bs,
    float* __restrict__ q, float* __restrict__ k,
    float* __restrict__ v, float* __restrict__ sk)
{
  __shared__ float xl[8][128];
  int blk = blockIdx.x, tid = threadIdx.x;
  int r0 = blk * 8;                       // 257 blocks * 8 rows = 2056 exactly
  const float4* src = reinterpret_cast<const float4*>(xf + r0 * 128);
  reinterpret_cast<float4*>(xl)[tid] = src[tid];
  __syncthreads();
  int j = tid & 127, g = tid >> 7;
  const float* Wm[4] = {Wq, Wk, Wv, Ws};
  const float* bm[4] = {bq, bk, bv, bs};
  float* om[4] = {q, k, v, sk};
  #pragma unroll
  for (int m = 0; m < 4; ++m) {
    float a[4];
    #pragma unroll
    for (int r = 0; r < 4; ++r) a[r] = bm[m][j];
    #pragma unroll 4
    for (int kk = 0; kk < 128; ++kk) {
      float w = Wm[m][kk * 128 + j];
      #pragma unroll
      for (int r = 0; r < 4; ++r) a[r] += xl[g * 4 + r][kk] * w;
    }
    #pragma unroll
    for (int r = 0; r < 4; ++r) om[m][(r0 + g * 4 + r) * 128 + j] = a[r];
  }
}

// ---------------- Kernel C: dense multiplicity-weighted attention + logits ---
__global__ __launch_bounds__(128) void k_attn(
    const float* __restrict__ q, const float* __restrict__ k,
    const float* __restrict__ v, const float* __restrict__ sk,
    const float* __restrict__ W_start, const float* __restrict__ b_start,
    const float* __restrict__ W_end, const float* __restrict__ b_end,
    float* __restrict__ out)
{
  int blk = blockIdx.x, tid = threadIdx.x;
  int b = blk >> 6;                       // 64 dst-groups per batch
  int dgrp = blk & 63;
  int base = b * 257;
  float qd[4], mr[4], den[4], acc[4];
  int dlist[4];
  #pragma unroll
  for (int r = 0; r < 4; ++r) {
    int d = 1 + dgrp * 4 + r;
    dlist[r] = d;
    qd[r] = q[(base + d) * 128 + tid];
    mr[r] = -3.0e38f; den[r] = 0.f; acc[r] = 0.f;
  }
  for (int s = 0; s < 256; ++s) {
    float kk = k[(base + s) * 128 + tid];
    float vv = v[(base + s) * 128 + tid];
    #pragma unroll
    for (int r = 0; r < 4; ++r) {
      int d = dlist[r];
      float p = qd[r] * kk;
      p += __shfl_xor(p, 1);
      p += __shfl_xor(p, 2);
      p += __shfl_xor(p, 4);
      p += __shfl_xor(p, 8);
      float logit = p * 0.25f;            // / sqrt(16)
      float cnt;
      if (d == 256) {
        cnt = (s == 0 ? 1.f : 0.f) + (s == 255 ? 1.f : 0.f);
      } else {
        cnt = (s != d ? 1.f : 0.f);       // semantic: all pairs
        if (s == 0) cnt += 1.f;           // query->segment edge
        if (s == d - 1) cnt += 2.f;       // qe cycle + temporal h=1 fwd
        if (s == d + 1 && d <= 254) cnt += 1.f;  // temporal h=1 bwd
        if (s == d - 2 && d >= 2)  cnt += 1.f;   // temporal h=2 fwd
        if (s == d + 2 && d <= 253) cnt += 1.f;  // temporal h=2 bwd
      }
      if (cnt > 0.f) {                    // uniform across block
        float nm = fmaxf(mr[r], logit);
        float sc = __expf(mr[r] - nm);
        float w = cnt * __expf(logit - nm);
        den[r] = den[r] * sc + w;
        acc[r] = acc[r] * sc + w * vv;
        mr[r] = nm;
      }
    }
  }
  __shared__ float reds[128], rede[128];
  float wst = W_start[tid], wen = W_end[tid];
  float bs0 = b_start[0], be0 = b_end[0];
  #pragma unroll
  for (int r = 0; r < 4; ++r) {
    int d = dlist[r];
    float o = acc[r] / (den[r] + 1e-16f) + sk[(base + d) * 128 + tid];
    reds[tid] = o * wst;
    rede[tid] = o * wen;
    __syncthreads();
    for (int off = 64; off > 0; off >>= 1) {
      if (tid < off) { reds[tid] += reds[tid + off]; rede[tid] += rede[tid + off]; }
      __syncthreads();
    }
    if (tid == 0) {
      out[b * 256 + (d - 1)] = reds[0] + bs0;
      out[2048 + b * 256 + (d - 1)] = rede[0] + be0;
    }
    __syncthreads();
  }
}

extern "C" void kernel_launch(void* const* d_in, const int* in_sizes, int n_in,
                              void* d_out, int out_size, void* d_ws, size_t ws_size,
                              hipStream_t stream) {
  const int*   word_ids = (const int*)d_in[0];
  const int*   char_ids = (const int*)d_in[1];
  const float* video    = (const float*)d_in[2];
  const float* v_mask   = (const float*)d_in[3];
  const float* q_mask   = (const float*)d_in[4];
  const float* word_emb = (const float*)d_in[5];
  const float* char_emb = (const float*)d_in[6];
  const float* W_embed  = (const float*)d_in[7];
  const float* b_embed  = (const float*)d_in[8];
  const float* W_vproj  = (const float*)d_in[9];
  const float* b_vproj  = (const float*)d_in[10];
  const float* W_enc    = (const float*)d_in[11];
  const float* b_enc    = (const float*)d_in[12];
  const float* Wq       = (const float*)d_in[13];
  const float* bq       = (const float*)d_in[14];
  const float* Wk       = (const float*)d_in[15];
  const float* bk       = (const float*)d_in[16];
  const float* Wv       = (const float*)d_in[17];
  const float* bv       = (const float*)d_in[18];
  const float* Wskip    = (const float*)d_in[19];
  const float* bskip    = (const float*)d_in[20];
  const float* W_start  = (const float*)d_in[21];
  const float* b_start  = (const float*)d_in[22];
  const float* W_end    = (const float*)d_in[23];
  const float* b_end    = (const float*)d_in[24];

  float* xf = (float*)d_ws;
  float* q  = xf + NN_ * DIM_;
  float* k  = q  + NN_ * DIM_;
  float* v  = k  + NN_ * DIM_;
  float* sk = v  + NN_ * DIM_;

  hipLaunchKernelGGL(k_nodes, dim3(264), dim3(256), 0, stream,
    word_ids, char_ids, video, v_mask, q_mask, word_emb, char_emb,
    W_embed, b_embed, W_vproj, b_vproj, W_enc, b_enc, xf);
  hipLaunchKernelGGL(k_proj, dim3(257), dim3(256), 0, stream,
    xf, Wq, bq, Wk, bk, Wv, bv, Wskip, bskip, q, k, v, sk);
  hipLaunchKernelGGL(k_attn, dim3(512), dim3(128), 0, stream,
    q, k, v, sk, W_start, b_start, W_end, b_end, (float*)d_out);
}

// Round 2
// 296.840 us; speedup vs baseline: 1.6211x; 1.6211x over previous
//
#include <hip/hip_runtime.h>
#include <hip/hip_bf16.h>
#include <math.h>

#define B_ 8
#define T_ 256
#define LQ_ 20
#define LC_ 10
#define DIM_ 128
#define N_ 257            // T+1
#define NN_ (B_*N_)       // 2056

// ---------------- Kernel A: node features (video + query branches) ----------
__global__ __launch_bounds__(256) void k_nodes(
    const int* __restrict__ word_ids, const int* __restrict__ char_ids,
    const float* __restrict__ video,
    const float* __restrict__ v_mask, const float* __restrict__ q_mask,
    const float* __restrict__ word_emb, const float* __restrict__ char_emb,
    const float* __restrict__ W_embed, const float* __restrict__ b_embed,
    const float* __restrict__ W_vproj, const float* __restrict__ b_vproj,
    const float* __restrict__ W_enc, const float* __restrict__ b_enc,
    float* __restrict__ xf)
{
  int blk = blockIdx.x;
  int tid = threadIdx.x;
  __shared__ float vlds[8 * 1024];       // 32 KB: 8 video rows
  __shared__ float hlds[8][128];
  __shared__ float emb[352];
  __shared__ float hq[128];

  if (blk < 256) {
    // ---- video branch: rows r0..r0+7 ----
    int r0 = blk * 8;
    const float4* src = reinterpret_cast<const float4*>(video + r0 * 1024);
    float4* dst4 = reinterpret_cast<float4*>(vlds);
    for (int idx = tid; idx < 2048; idx += 256) dst4[idx] = src[idx];
    __syncthreads();
    int j = tid & 127, g = tid >> 7;
    float acc[4];
    #pragma unroll
    for (int r = 0; r < 4; ++r) acc[r] = b_vproj[j];
    #pragma unroll 8
    for (int k = 0; k < 1024; ++k) {
      float w = W_vproj[k * 128 + j];
      #pragma unroll
      for (int r = 0; r < 4; ++r) acc[r] += vlds[(g * 4 + r) * 1024 + k] * w;
    }
    #pragma unroll
    for (int r = 0; r < 4; ++r) hlds[g * 4 + r][j] = acc[r];
    __syncthreads();
    float out[4];
    #pragma unroll
    for (int r = 0; r < 4; ++r) out[r] = b_enc[j];
    #pragma unroll 4
    for (int k = 0; k < 128; ++k) {
      float w = W_enc[k * 128 + j];
      #pragma unroll
      for (int r = 0; r < 4; ++r) out[r] += hlds[g * 4 + r][k] * w;
    }
    #pragma unroll
    for (int r = 0; r < 4; ++r) {
      int vr = r0 + g * 4 + r;
      int bi = vr >> 8, t = vr & 255;
      float e = fmaxf(out[r], 0.f) * v_mask[vr];
      xf[(bi * 257 + 1 + t) * 128 + j] = e;
    }
  } else {
    // ---- query branch: one block per batch ----
    int b = blk - 256;
    int j = tid & 127;
    float qacc = 0.f;
    for (int lq = 0; lq < LQ_; ++lq) {
      int wid = word_ids[b * LQ_ + lq];
      for (int m = tid; m < 300; m += 256) emb[m] = word_emb[wid * 300 + m];
      for (int c = tid; c < 50; c += 256) {
        float s = 0.f;
        #pragma unroll
        for (int l = 0; l < 10; ++l) {
          int cid = char_ids[(b * LQ_ + lq) * 10 + l];
          s += char_emb[cid * 50 + c];
        }
        emb[300 + c] = s * 0.1f;
      }
      __syncthreads();
      if (tid < 128) {
        float h = b_embed[j];
        for (int m = 0; m < 350; ++m) h += emb[m] * W_embed[m * 128 + j];
        hq[j] = h;
      }
      __syncthreads();
      if (tid < 128) {
        float e = b_enc[j];
        #pragma unroll 4
        for (int k = 0; k < 128; ++k) e += hq[k] * W_enc[k * 128 + j];
        e = fmaxf(e, 0.f) * q_mask[b * LQ_ + lq];
        qacc += e;
      }
      __syncthreads();
    }
    if (tid < 128) xf[(b * 257) * 128 + j] = qacc * (1.f / LQ_);
  }
}

// ---------------- Kernel B: q/k/v/skip projections ---------------------------
__global__ __launch_bounds__(256) void k_proj(
    const float* __restrict__ xf,
    const float* __restrict__ Wq, const float* __restrict__ bq,
    const float* __restrict__ Wk, const float* __restrict__ bk,
    const float* __restrict__ Wv, const float* __restrict__ bv,
    const float* __restrict__ Ws, const float* __restrict__ bs,
    float* __restrict__ q, float* __restrict__ k,
    float* __restrict__ v, float* __restrict__ sk)
{
  __shared__ float xl[8][128];
  int blk = blockIdx.x, tid = threadIdx.x;
  int r0 = blk * 8;                       // 257 blocks * 8 rows = 2056 exactly
  const float4* src = reinterpret_cast<const float4*>(xf + r0 * 128);
  reinterpret_cast<float4*>(xl)[tid] = src[tid];
  __syncthreads();
  int j = tid & 127, g = tid >> 7;
  const float* Wm[4] = {Wq, Wk, Wv, Ws};
  const float* bm[4] = {bq, bk, bv, bs};
  float* om[4] = {q, k, v, sk};
  #pragma unroll
  for (int m = 0; m < 4; ++m) {
    float a[4];
    #pragma unroll
    for (int r = 0; r < 4; ++r) a[r] = bm[m][j];
    #pragma unroll 4
    for (int kk = 0; kk < 128; ++kk) {
      float w = Wm[m][kk * 128 + j];
      #pragma unroll
      for (int r = 0; r < 4; ++r) a[r] += xl[g * 4 + r][kk] * w;
    }
    #pragma unroll
    for (int r = 0; r < 4; ++r) om[m][(r0 + g * 4 + r) * 128 + j] = a[r];
  }
}

// ---------------- edge multiplicity (verified round 1) -----------------------
__device__ __forceinline__ float cntf(int dnode, int s) {
  if (dnode == 256) return (s == 0 ? 1.f : 0.f) + (s == 255 ? 1.f : 0.f);
  float c = (s != dnode) ? 1.f : 0.f;          // semantic all-pairs (nodes 0..255)
  if (s == 0) c += 1.f;                        // query->segment
  if (s == dnode - 1) c += 2.f;                // qe chain + temporal h=1 fwd
  if (s == dnode + 1 && dnode <= 254) c += 1.f;// temporal h=1 bwd
  if (s == dnode - 2 && dnode >= 2) c += 1.f;  // temporal h=2 fwd
  if (s == dnode + 2 && dnode <= 253) c += 1.f;// temporal h=2 bwd
  return c;
}

// ---------------- Kernel C: fused dense attention, no inner-loop shuffles ----
// grid (16 dst-tiles, 8 batches), 256 threads.
// Phase A lanes = (dst,head): logits tiny => exp without max-subtract is exact.
__global__ __launch_bounds__(256) void k_attn2(
    const float* __restrict__ q, const float* __restrict__ k,
    const float* __restrict__ v, const float* __restrict__ sk,
    const float* __restrict__ W_start, const float* __restrict__ b_start,
    const float* __restrict__ W_end, const float* __restrict__ b_end,
    float* __restrict__ out)
{
  __shared__ float P_l[128][66];     // [dd*8+h][s in tile], pad 66: float2-aligned, conflict-free reads
  __shared__ float den_l[2][16][8];
  __shared__ float comb[16][128];
  __shared__ float red[16][2][2];

  const int b = blockIdx.y;
  const int d0 = blockIdx.x * 16;
  const int tid = threadIdx.x;
  const int base = b * 257;

  // phase-A mapping: wave w, lane l -> (dd, h, s-half)
  const int wA = tid >> 6, lA = tid & 63;
  const int ddA = lA >> 2, hsA = lA & 3;
  const int hA = (wA & 1) * 4 + hsA;
  const int shA = wA >> 1;
  const int dnodeA = d0 + ddA + 1;
  // phase-B mapping: lane = dim
  const int jB = tid & 127, shB = tid >> 7, hB = jB >> 4;

  // hoist this thread's Q fragment (16 floats) into registers once
  const float* qrow = q + (base + dnodeA) * 128 + hA * 16;
  const float4 qq0 = *(const float4*)(qrow + 0);
  const float4 qq1 = *(const float4*)(qrow + 4);
  const float4 qq2 = *(const float4*)(qrow + 8);
  const float4 qq3 = *(const float4*)(qrow + 12);

  float denr = 0.f;
  float accB[16];
  #pragma unroll
  for (int i = 0; i < 16; ++i) accB[i] = 0.f;

  for (int tile = 0; tile < 4; ++tile) {
    const int s0 = tile * 64;
    // ---- phase A: weights into LDS ----
    #pragma unroll 2
    for (int si = 0; si < 32; ++si) {
      const int s = shA * 32 + si;
      const float* krow = k + (base + s0 + s) * 128 + hA * 16;
      const float4 k0 = *(const float4*)(krow + 0);
      const float4 k1 = *(const float4*)(krow + 4);
      const float4 k2 = *(const float4*)(krow + 8);
      const float4 k3 = *(const float4*)(krow + 12);
      float dt = qq0.x*k0.x + qq0.y*k0.y + qq0.z*k0.z + qq0.w*k0.w
               + qq1.x*k1.x + qq1.y*k1.y + qq1.z*k1.z + qq1.w*k1.w
               + qq2.x*k2.x + qq2.y*k2.y + qq2.z*k2.z + qq2.w*k2.w
               + qq3.x*k3.x + qq3.y*k3.y + qq3.z*k3.z + qq3.w*k3.w;
      const float c = cntf(dnodeA, s0 + s);
      const float wv = c * __expf(dt * 0.25f);
      P_l[ddA * 8 + hA][s] = wv;
      denr += wv;
    }
    __syncthreads();
    // ---- phase B: acc += P * V ----
    for (int si2 = 0; si2 < 16; ++si2) {
      const int s = shB * 32 + si2 * 2;
      const float va = v[(base + s0 + s) * 128 + jB];
      const float vb = v[(base + s0 + s + 1) * 128 + jB];
      #pragma unroll
      for (int dd = 0; dd < 16; ++dd) {
        const float2 pw = *(const float2*)&P_l[dd * 8 + hB][s];
        accB[dd] += pw.x * va + pw.y * vb;
      }
    }
    __syncthreads();
  }

  den_l[shA][ddA][hA] = denr;
  __syncthreads();
  if (shB == 1) {
    #pragma unroll
    for (int dd = 0; dd < 16; ++dd) comb[dd][jB] = accB[dd];
  }
  __syncthreads();
  if (shB == 0) {
    const float wst = W_start[jB], wen = W_end[jB];
    #pragma unroll
    for (int dd = 0; dd < 16; ++dd) {
      const float den = den_l[0][dd][hB] + den_l[1][dd][hB];
      const float o = (accB[dd] + comb[dd][jB]) / (den + 1e-16f)
                    + sk[(base + d0 + dd + 1) * 128 + jB];
      float ps = o * wst, pe = o * wen;
      #pragma unroll
      for (int off = 1; off < 64; off <<= 1) {
        ps += __shfl_xor(ps, off);
        pe += __shfl_xor(pe, off);
      }
      if ((jB & 63) == 0) { red[dd][jB >> 6][0] = ps; red[dd][jB >> 6][1] = pe; }
    }
  }
  __syncthreads();
  if (tid < 16) {
    out[b * 256 + d0 + tid]        = red[tid][0][0] + red[tid][1][0] + b_start[0];
    out[2048 + b * 256 + d0 + tid] = red[tid][0][1] + red[tid][1][1] + b_end[0];
  }
}

extern "C" void kernel_launch(void* const* d_in, const int* in_sizes, int n_in,
                              void* d_out, int out_size, void* d_ws, size_t ws_size,
                              hipStream_t stream) {
  const int*   word_ids = (const int*)d_in[0];
  const int*   char_ids = (const int*)d_in[1];
  const float* video    = (const float*)d_in[2];
  const float* v_mask   = (const float*)d_in[3];
  const float* q_mask   = (const float*)d_in[4];
  const float* word_emb = (const float*)d_in[5];
  const float* char_emb = (const float*)d_in[6];
  const float* W_embed  = (const float*)d_in[7];
  const float* b_embed  = (const float*)d_in[8];
  const float* W_vproj  = (const float*)d_in[9];
  const float* b_vproj  = (const float*)d_in[10];
  const float* W_enc    = (const float*)d_in[11];
  const float* b_enc    = (const float*)d_in[12];
  const float* Wq       = (const float*)d_in[13];
  const float* bq       = (const float*)d_in[14];
  const float* Wk       = (const float*)d_in[15];
  const float* bk       = (const float*)d_in[16];
  const float* Wv       = (const float*)d_in[17];
  const float* bv       = (const float*)d_in[18];
  const float* Wskip    = (const float*)d_in[19];
  const float* bskip    = (const float*)d_in[20];
  const float* W_start  = (const float*)d_in[21];
  const float* b_start  = (const float*)d_in[22];
  const float* W_end    = (const float*)d_in[23];
  const float* b_end    = (const float*)d_in[24];

  float* xf = (float*)d_ws;
  float* q  = xf + NN_ * DIM_;
  float* k  = q  + NN_ * DIM_;
  float* v  = k  + NN_ * DIM_;
  float* sk = v  + NN_ * DIM_;

  hipLaunchKernelGGL(k_nodes, dim3(264), dim3(256), 0, stream,
    word_ids, char_ids, video, v_mask, q_mask, word_emb, char_emb,
    W_embed, b_embed, W_vproj, b_vproj, W_enc, b_enc, xf);
  hipLaunchKernelGGL(k_proj, dim3(257), dim3(256), 0, stream,
    xf, Wq, bq, Wk, bk, Wv, bv, Wskip, bskip, q, k, v, sk);
  hipLaunchKernelGGL(k_attn2, dim3(16, 8), dim3(256), 0, stream,
    q, k, v, sk, W_start, b_start, W_end, b_end, (float*)d_out);
}

// Round 3
// 181.324 us; speedup vs baseline: 2.6538x; 1.6371x over previous
//
#include <hip/hip_runtime.h>
#include <hip/hip_bf16.h>
#include <math.h>

#define B_ 8
#define T_ 256
#define LQ_ 20
#define LC_ 10
#define DIM_ 128
#define N_ 257            // T+1
#define NN_ (B_*N_)       // 2056

// ---------------- kA: video @ W_vproj, split-K partials ----------------------
// grid (128 row-tiles of 16, 8 k-splits of 128), 256 thr.
// thread: jc=tid&31 -> cols 4jc..4jc+3 (float4 W), rg=tid>>5 -> rows 2rg,2rg+1.
__global__ __launch_bounds__(256) void kA_vpart(
    const float* __restrict__ video, const float* __restrict__ Wv,
    float* __restrict__ part)
{
  __shared__ float Vl[16][128];
  const int rt = blockIdx.x, ks = blockIdx.y;
  const int tid = threadIdx.x;
  const int r0 = rt * 16;
  for (int idx4 = tid; idx4 < 512; idx4 += 256) {
    const int i = idx4 >> 5, f = idx4 & 31;
    reinterpret_cast<float4*>(&Vl[i][0])[f] =
      reinterpret_cast<const float4*>(video + (size_t)(r0 + i) * 1024 + ks * 128)[f];
  }
  __syncthreads();
  const int jc = tid & 31, rg = tid >> 5;
  const int ra = rg * 2, rb = ra + 1;
  const float4* W4 = reinterpret_cast<const float4*>(Wv + (size_t)ks * 128 * 128) + jc;
  float4 a0 = {0,0,0,0}, a1 = {0,0,0,0};
  #pragma unroll 8
  for (int k = 0; k < 128; ++k) {
    const float4 w = W4[k * 32];
    const float x0 = Vl[ra][k], x1 = Vl[rb][k];
    a0.x += x0*w.x; a0.y += x0*w.y; a0.z += x0*w.z; a0.w += x0*w.w;
    a1.x += x1*w.x; a1.y += x1*w.y; a1.z += x1*w.z; a1.w += x1*w.w;
  }
  float* pa = part + (((size_t)ks * 2048) + r0 + ra) * 128 + 4 * jc;
  float* pb = part + (((size_t)ks * 2048) + r0 + rb) * 128 + 4 * jc;
  *reinterpret_cast<float4*>(pa) = a0;
  *reinterpret_cast<float4*>(pb) = a1;
}

// ---------------- kB: reduce partials + bias -> h; h @ W_enc -> relu*mask -> xf
// grid 1024 (2 video rows each), 256 thr.
__global__ __launch_bounds__(256) void kB_enc(
    const float* __restrict__ part, const float* __restrict__ bv,
    const float* __restrict__ We, const float* __restrict__ be,
    const float* __restrict__ vmask, float* __restrict__ xf)
{
  __shared__ float h[2][128];
  __shared__ float ps[4][2][128];
  const int blk = blockIdx.x, tid = threadIdx.x;
  const int rloc = tid >> 7, col = tid & 127;
  const int row = 2 * blk + rloc;
  float s = bv[col];
  #pragma unroll
  for (int ks = 0; ks < 8; ++ks) s += part[((size_t)ks * 2048 + row) * 128 + col];
  h[rloc][col] = s;
  __syncthreads();
  const int jc = tid & 31, rg = tid >> 5;
  const int r = rg & 1, ksub = rg >> 1;
  const float4* W4 = reinterpret_cast<const float4*>(We) + jc;
  float4 a = {0,0,0,0};
  #pragma unroll 8
  for (int kk = 0; kk < 32; ++kk) {
    const int k = ksub * 32 + kk;
    const float4 w = W4[k * 32];
    const float x = h[r][k];
    a.x += x*w.x; a.y += x*w.y; a.z += x*w.z; a.w += x*w.w;
  }
  reinterpret_cast<float4*>(&ps[ksub][r][0])[jc] = a;
  __syncthreads();
  float e = be[col] + ps[0][rloc][col] + ps[1][rloc][col] + ps[2][rloc][col] + ps[3][rloc][col];
  const int vr = 2 * blk + rloc;
  e = fmaxf(e, 0.f) * vmask[vr];
  const int b = vr >> 8, t = vr & 255;
  xf[((size_t)b * 257 + 1 + t) * 128 + col] = e;
}

// ---------------- kQ: query branch, 8 blocks x 512 thr (lq parallel x4) ------
__global__ __launch_bounds__(512) void kQ(
    const int* __restrict__ word_ids, const int* __restrict__ char_ids,
    const float* __restrict__ q_mask,
    const float* __restrict__ word_emb, const float* __restrict__ char_emb,
    const float* __restrict__ W_embed, const float* __restrict__ b_embed,
    const float* __restrict__ We, const float* __restrict__ be,
    float* __restrict__ xf)
{
  __shared__ float emb[4][352];
  __shared__ float hq[4][128];
  __shared__ float qp[4][128];
  const int b = blockIdx.x, tid = threadIdx.x;
  const int g = tid >> 7, j = tid & 127;
  float qacc = 0.f;
  for (int it = 0; it < 5; ++it) {
    const int lq = g + it * 4;
    const int wid = word_ids[b * LQ_ + lq];
    for (int m = j; m < 300; m += 128) emb[g][m] = word_emb[(size_t)wid * 300 + m];
    if (j < 50) {
      float s = 0.f;
      #pragma unroll
      for (int l = 0; l < 10; ++l) {
        const int cid = char_ids[(b * LQ_ + lq) * 10 + l];
        s += char_emb[cid * 50 + j];
      }
      emb[g][300 + j] = s * 0.1f;
    }
    __syncthreads();
    float hv = b_embed[j];
    #pragma unroll 5
    for (int m = 0; m < 350; ++m) hv += emb[g][m] * W_embed[m * 128 + j];
    hq[g][j] = hv;
    __syncthreads();
    float e = be[j];
    #pragma unroll 4
    for (int k = 0; k < 128; ++k) e += hq[g][k] * We[k * 128 + j];
    qacc += fmaxf(e, 0.f) * q_mask[b * LQ_ + lq];
    __syncthreads();
  }
  qp[g][j] = qacc;
  __syncthreads();
  if (g == 0)
    xf[((size_t)b * 257) * 128 + j] = (qp[0][j] + qp[1][j] + qp[2][j] + qp[3][j]) * (1.f / LQ_);
}

// ---------------- kP: q/k/v/skip projections, float4-W, 514 blocks -----------
// thread: jc=tid&31 (4 cols), rg=tid>>5: m=rg&3 (matrix), rh=rg>>2 (row pair).
__global__ __launch_bounds__(256) void kP(
    const float* __restrict__ xf,
    const float* __restrict__ Wq, const float* __restrict__ bq,
    const float* __restrict__ Wk, const float* __restrict__ bk,
    const float* __restrict__ Wv, const float* __restrict__ bv,
    const float* __restrict__ Ws, const float* __restrict__ bs,
    float* __restrict__ q, float* __restrict__ k,
    float* __restrict__ v, float* __restrict__ sk)
{
  __shared__ float xl[4][128];
  const int blk = blockIdx.x, tid = threadIdx.x;
  const int r0 = blk * 4;
  if (tid < 128)
    reinterpret_cast<float4*>(xl)[tid] =
      reinterpret_cast<const float4*>(xf + (size_t)r0 * 128)[tid];
  __syncthreads();
  const int jc = tid & 31, rg = tid >> 5;
  const int m = rg & 3, rh = rg >> 2;
  const int ra = rh * 2, rb = ra + 1;
  const float* Wm[4] = {Wq, Wk, Wv, Ws};
  const float* bm[4] = {bq, bk, bv, bs};
  float* om[4] = {q, k, v, sk};
  const float4* W4 = reinterpret_cast<const float4*>(Wm[m]) + jc;
  float4 a0 = {0,0,0,0}, a1 = {0,0,0,0};
  #pragma unroll 8
  for (int kk = 0; kk < 128; ++kk) {
    const float4 w = W4[kk * 32];
    const float x0 = xl[ra][kk], x1 = xl[rb][kk];
    a0.x += x0*w.x; a0.y += x0*w.y; a0.z += x0*w.z; a0.w += x0*w.w;
    a1.x += x1*w.x; a1.y += x1*w.y; a1.z += x1*w.z; a1.w += x1*w.w;
  }
  const float4 bb = reinterpret_cast<const float4*>(bm[m])[jc];
  a0.x += bb.x; a0.y += bb.y; a0.z += bb.z; a0.w += bb.w;
  a1.x += bb.x; a1.y += bb.y; a1.z += bb.z; a1.w += bb.w;
  *reinterpret_cast<float4*>(om[m] + (size_t)(r0 + ra) * 128 + 4 * jc) = a0;
  *reinterpret_cast<float4*>(om[m] + (size_t)(r0 + rb) * 128 + 4 * jc) = a1;
}

// ---------------- edge multiplicity (verified round 1) -----------------------
__device__ __forceinline__ float cntf(int dnode, int s) {
  if (dnode == 256) return (s == 0 ? 1.f : 0.f) + (s == 255 ? 1.f : 0.f);
  float c = (s != dnode) ? 1.f : 0.f;          // semantic all-pairs (nodes 0..255)
  if (s == 0) c += 1.f;                        // query->segment
  if (s == dnode - 1) c += 2.f;                // qe chain + temporal h=1 fwd
  if (s == dnode + 1 && dnode <= 254) c += 1.f;// temporal h=1 bwd
  if (s == dnode - 2 && dnode >= 2) c += 1.f;  // temporal h=2 fwd
  if (s == dnode + 2 && dnode <= 253) c += 1.f;// temporal h=2 bwd
  return c;
}

// ---------------- k_attn2: fused dense attention (verified round 2) ----------
__global__ __launch_bounds__(256) void k_attn2(
    const float* __restrict__ q, const float* __restrict__ k,
    const float* __restrict__ v, const float* __restrict__ sk,
    const float* __restrict__ W_start, const float* __restrict__ b_start,
    const float* __restrict__ W_end, const float* __restrict__ b_end,
    float* __restrict__ out)
{
  __shared__ float P_l[128][66];
  __shared__ float den_l[2][16][8];
  __shared__ float comb[16][128];
  __shared__ float red[16][2][2];

  const int b = blockIdx.y;
  const int d0 = blockIdx.x * 16;
  const int tid = threadIdx.x;
  const int base = b * 257;

  const int wA = tid >> 6, lA = tid & 63;
  const int ddA = lA >> 2, hsA = lA & 3;
  const int hA = (wA & 1) * 4 + hsA;
  const int shA = wA >> 1;
  const int dnodeA = d0 + ddA + 1;
  const int jB = tid & 127, shB = tid >> 7, hB = jB >> 4;

  const float* qrow = q + (base + dnodeA) * 128 + hA * 16;
  const float4 qq0 = *(const float4*)(qrow + 0);
  const float4 qq1 = *(const float4*)(qrow + 4);
  const float4 qq2 = *(const float4*)(qrow + 8);
  const float4 qq3 = *(const float4*)(qrow + 12);

  float denr = 0.f;
  float accB[16];
  #pragma unroll
  for (int i = 0; i < 16; ++i) accB[i] = 0.f;

  for (int tile = 0; tile < 4; ++tile) {
    const int s0 = tile * 64;
    #pragma unroll 2
    for (int si = 0; si < 32; ++si) {
      const int s = shA * 32 + si;
      const float* krow = k + (base + s0 + s) * 128 + hA * 16;
      const float4 k0 = *(const float4*)(krow + 0);
      const float4 k1 = *(const float4*)(krow + 4);
      const float4 k2 = *(const float4*)(krow + 8);
      const float4 k3 = *(const float4*)(krow + 12);
      float dt = qq0.x*k0.x + qq0.y*k0.y + qq0.z*k0.z + qq0.w*k0.w
               + qq1.x*k1.x + qq1.y*k1.y + qq1.z*k1.z + qq1.w*k1.w
               + qq2.x*k2.x + qq2.y*k2.y + qq2.z*k2.z + qq2.w*k2.w
               + qq3.x*k3.x + qq3.y*k3.y + qq3.z*k3.z + qq3.w*k3.w;
      const float c = cntf(dnodeA, s0 + s);
      const float wv = c * __expf(dt * 0.25f);
      P_l[ddA * 8 + hA][s] = wv;
      denr += wv;
    }
    __syncthreads();
    for (int si2 = 0; si2 < 16; ++si2) {
      const int s = shB * 32 + si2 * 2;
      const float va = v[(base + s0 + s) * 128 + jB];
      const float vb = v[(base + s0 + s + 1) * 128 + jB];
      #pragma unroll
      for (int dd = 0; dd < 16; ++dd) {
        const float2 pw = *(const float2*)&P_l[dd * 8 + hB][s];
        accB[dd] += pw.x * va + pw.y * vb;
      }
    }
    __syncthreads();
  }

  den_l[shA][ddA][hA] = denr;
  __syncthreads();
  if (shB == 1) {
    #pragma unroll
    for (int dd = 0; dd < 16; ++dd) comb[dd][jB] = accB[dd];
  }
  __syncthreads();
  if (shB == 0) {
    const float wst = W_start[jB], wen = W_end[jB];
    #pragma unroll
    for (int dd = 0; dd < 16; ++dd) {
      const float den = den_l[0][dd][hB] + den_l[1][dd][hB];
      const float o = (accB[dd] + comb[dd][jB]) / (den + 1e-16f)
                    + sk[(base + d0 + dd + 1) * 128 + jB];
      float ps = o * wst, pe = o * wen;
      #pragma unroll
      for (int off = 1; off < 64; off <<= 1) {
        ps += __shfl_xor(ps, off);
        pe += __shfl_xor(pe, off);
      }
      if ((jB & 63) == 0) { red[dd][jB >> 6][0] = ps; red[dd][jB >> 6][1] = pe; }
    }
  }
  __syncthreads();
  if (tid < 16) {
    out[b * 256 + d0 + tid]        = red[tid][0][0] + red[tid][1][0] + b_start[0];
    out[2048 + b * 256 + d0 + tid] = red[tid][0][1] + red[tid][1][1] + b_end[0];
  }
}

extern "C" void kernel_launch(void* const* d_in, const int* in_sizes, int n_in,
                              void* d_out, int out_size, void* d_ws, size_t ws_size,
                              hipStream_t stream) {
  const int*   word_ids = (const int*)d_in[0];
  const int*   char_ids = (const int*)d_in[1];
  const float* video    = (const float*)d_in[2];
  const float* v_mask   = (const float*)d_in[3];
  const float* q_mask   = (const float*)d_in[4];
  const float* word_emb = (const float*)d_in[5];
  const float* char_emb = (const float*)d_in[6];
  const float* W_embed  = (const float*)d_in[7];
  const float* b_embed  = (const float*)d_in[8];
  const float* W_vproj  = (const float*)d_in[9];
  const float* b_vproj  = (const float*)d_in[10];
  const float* W_enc    = (const float*)d_in[11];
  const float* b_enc    = (const float*)d_in[12];
  const float* Wq       = (const float*)d_in[13];
  const float* bq       = (const float*)d_in[14];
  const float* Wk       = (const float*)d_in[15];
  const float* bk       = (const float*)d_in[16];
  const float* Wv       = (const float*)d_in[17];
  const float* bv       = (const float*)d_in[18];
  const float* Wskip    = (const float*)d_in[19];
  const float* bskip    = (const float*)d_in[20];
  const float* W_start  = (const float*)d_in[21];
  const float* b_start  = (const float*)d_in[22];
  const float* W_end    = (const float*)d_in[23];
  const float* b_end    = (const float*)d_in[24];

  float* xf   = (float*)d_ws;
  float* q    = xf + NN_ * DIM_;
  float* k    = q  + NN_ * DIM_;
  float* v    = k  + NN_ * DIM_;
  float* sk   = v  + NN_ * DIM_;
  float* part = sk + NN_ * DIM_;   // 8 * 2048 * 128 floats = 8 MB

  hipLaunchKernelGGL(kA_vpart, dim3(128, 8), dim3(256), 0, stream,
    video, W_vproj, part);
  hipLaunchKernelGGL(kB_enc, dim3(1024), dim3(256), 0, stream,
    part, b_vproj, W_enc, b_enc, v_mask, xf);
  hipLaunchKernelGGL(kQ, dim3(8), dim3(512), 0, stream,
    word_ids, char_ids, q_mask, word_emb, char_emb,
    W_embed, b_embed, W_enc, b_enc, xf);
  hipLaunchKernelGGL(kP, dim3(514), dim3(256), 0, stream,
    xf, Wq, bq, Wk, bk, Wv, bv, Wskip, bskip, q, k, v, sk);
  hipLaunchKernelGGL(k_attn2, dim3(16, 8), dim3(256), 0, stream,
    q, k, v, sk, W_start, b_start, W_end, b_end, (float*)d_out);
}

// Round 4
// 110.327 us; speedup vs baseline: 4.3615x; 1.6435x over previous
//
#include <hip/hip_runtime.h>
#include <hip/hip_bf16.h>
#include <math.h>

#define B_ 8
#define T_ 256
#define LQ_ 20
#define LC_ 10
#define DIM_ 128
#define N_ 257            // T+1
#define NN_ (B_*N_)       // 2056

// ---------------- kAQ: video @ W_vproj split-K  ∪  query per-(b,lq) rows -----
// blocks 0..1023: video partials (rt=blk&127, ks=blk>>7), 16 rows x 128 k-slice
// blocks 1024..1183: query row qi=blk-1024 -> eq[qi][128]
__global__ __launch_bounds__(256) void kAQ(
    const float* __restrict__ video, const float* __restrict__ Wv,
    const int* __restrict__ word_ids, const int* __restrict__ char_ids,
    const float* __restrict__ word_emb, const float* __restrict__ char_emb,
    const float* __restrict__ W_embed, const float* __restrict__ b_embed,
    const float* __restrict__ We, const float* __restrict__ be,
    const float* __restrict__ q_mask,
    float* __restrict__ part, float* __restrict__ eq)
{
  __shared__ float smem[16 * 128];
  const int blk = blockIdx.x, tid = threadIdx.x;
  if (blk < 1024) {
    float (*Vl)[128] = reinterpret_cast<float(*)[128]>(smem);
    const int rt = blk & 127, ks = blk >> 7;
    const int r0 = rt * 16;
    for (int idx4 = tid; idx4 < 512; idx4 += 256) {
      const int i = idx4 >> 5, f = idx4 & 31;
      reinterpret_cast<float4*>(&Vl[i][0])[f] =
        reinterpret_cast<const float4*>(video + (size_t)(r0 + i) * 1024 + ks * 128)[f];
    }
    __syncthreads();
    const int jc = tid & 31, rg = tid >> 5;
    const int ra = rg * 2, rb = ra + 1;
    const float4* W4 = reinterpret_cast<const float4*>(Wv + (size_t)ks * 128 * 128) + jc;
    float4 a0 = {0,0,0,0}, a1 = {0,0,0,0};
    #pragma unroll 8
    for (int k = 0; k < 128; ++k) {
      const float4 w = W4[k * 32];
      const float x0 = Vl[ra][k], x1 = Vl[rb][k];
      a0.x += x0*w.x; a0.y += x0*w.y; a0.z += x0*w.z; a0.w += x0*w.w;
      a1.x += x1*w.x; a1.y += x1*w.y; a1.z += x1*w.z; a1.w += x1*w.w;
    }
    *reinterpret_cast<float4*>(part + (((size_t)ks * 2048) + r0 + ra) * 128 + 4 * jc) = a0;
    *reinterpret_cast<float4*>(part + (((size_t)ks * 2048) + r0 + rb) * 128 + 4 * jc) = a1;
  } else {
    const int qi = blk - 1024;
    const int b = qi / 20, lq = qi - b * 20;
    float* emb = smem;            // [352]
    float* ps  = smem + 352;      // [2][128]
    float* hl  = smem + 608;      // [128]
    float* pe  = smem + 736;      // [2][128]
    const int wid = word_ids[b * LQ_ + lq];
    for (int m = tid; m < 300; m += 256) emb[m] = word_emb[(size_t)wid * 300 + m];
    if (tid < 50) {
      float s = 0.f;
      #pragma unroll
      for (int l = 0; l < 10; ++l) {
        const int cid = char_ids[(b * LQ_ + lq) * 10 + l];
        s += char_emb[cid * 50 + tid];
      }
      emb[300 + tid] = s * 0.1f;
    }
    __syncthreads();
    const int j = tid & 127, half = tid >> 7;
    float a = 0.f;
    const float* Wcol = W_embed + (size_t)(half * 175) * 128 + j;
    const float* eh = emb + half * 175;
    #pragma unroll 5
    for (int m = 0; m < 175; ++m) a += eh[m] * Wcol[(size_t)m * 128];
    ps[half * 128 + j] = a;
    __syncthreads();
    if (tid < 128) hl[tid] = ps[tid] + ps[128 + tid] + b_embed[tid];
    __syncthreads();
    float e = 0.f;
    #pragma unroll 8
    for (int kk = 0; kk < 64; ++kk)
      e += hl[half * 64 + kk] * We[(half * 64 + kk) * 128 + j];
    pe[half * 128 + j] = e;
    __syncthreads();
    if (tid < 128) {
      float ev = pe[tid] + pe[128 + tid] + be[tid];
      ev = fmaxf(ev, 0.f) * q_mask[b * LQ_ + lq];
      eq[(size_t)qi * 128 + tid] = ev;
    }
  }
}

// ---------------- kBR: reduce video partials + enc  ∪  query mean ------------
// blocks 0..1023: 2 video rows each; blocks 1024..1031: qfeat[b] = mean(eq rows)
__global__ __launch_bounds__(256) void kBR(
    const float* __restrict__ part, const float* __restrict__ bv,
    const float* __restrict__ We, const float* __restrict__ be,
    const float* __restrict__ vmask, const float* __restrict__ eq,
    float* __restrict__ xf)
{
  __shared__ float h[2][128];
  __shared__ float ps[4][2][128];
  const int blk = blockIdx.x, tid = threadIdx.x;
  if (blk < 1024) {
    const int rloc = tid >> 7, col = tid & 127;
    const int row = 2 * blk + rloc;
    float s = bv[col];
    #pragma unroll
    for (int ks = 0; ks < 8; ++ks) s += part[((size_t)ks * 2048 + row) * 128 + col];
    h[rloc][col] = s;
    __syncthreads();
    const int jc = tid & 31, rg = tid >> 5;
    const int r = rg & 1, ksub = rg >> 1;
    const float4* W4 = reinterpret_cast<const float4*>(We) + jc;
    float4 a = {0,0,0,0};
    #pragma unroll 8
    for (int kk = 0; kk < 32; ++kk) {
      const int k = ksub * 32 + kk;
      const float4 w = W4[k * 32];
      const float x = h[r][k];
      a.x += x*w.x; a.y += x*w.y; a.z += x*w.z; a.w += x*w.w;
    }
    reinterpret_cast<float4*>(&ps[ksub][r][0])[jc] = a;
    __syncthreads();
    float e = be[col] + ps[0][rloc][col] + ps[1][rloc][col] + ps[2][rloc][col] + ps[3][rloc][col];
    const int vr = 2 * blk + rloc;
    e = fmaxf(e, 0.f) * vmask[vr];
    const int b = vr >> 8, t = vr & 255;
    xf[((size_t)b * 257 + 1 + t) * 128 + col] = e;
  } else {
    const int b = blk - 1024;
    if (tid < 128) {
      float s = 0.f;
      #pragma unroll 4
      for (int lq = 0; lq < LQ_; ++lq) s += eq[((size_t)b * LQ_ + lq) * 128 + tid];
      xf[((size_t)b * 257) * 128 + tid] = s * (1.f / LQ_);
    }
  }
}

// ---------------- kP: q/k/v/skip projections, float4-W, 514 blocks -----------
__global__ __launch_bounds__(256) void kP(
    const float* __restrict__ xf,
    const float* __restrict__ Wq, const float* __restrict__ bq,
    const float* __restrict__ Wk, const float* __restrict__ bk,
    const float* __restrict__ Wv, const float* __restrict__ bv,
    const float* __restrict__ Ws, const float* __restrict__ bs,
    float* __restrict__ q, float* __restrict__ k,
    float* __restrict__ v, float* __restrict__ sk)
{
  __shared__ float xl[4][128];
  const int blk = blockIdx.x, tid = threadIdx.x;
  const int r0 = blk * 4;
  if (tid < 128)
    reinterpret_cast<float4*>(xl)[tid] =
      reinterpret_cast<const float4*>(xf + (size_t)r0 * 128)[tid];
  __syncthreads();
  const int jc = tid & 31, rg = tid >> 5;
  const int m = rg & 3, rh = rg >> 2;
  const int ra = rh * 2, rb = ra + 1;
  const float* Wm[4] = {Wq, Wk, Wv, Ws};
  const float* bm[4] = {bq, bk, bv, bs};
  float* om[4] = {q, k, v, sk};
  const float4* W4 = reinterpret_cast<const float4*>(Wm[m]) + jc;
  float4 a0 = {0,0,0,0}, a1 = {0,0,0,0};
  #pragma unroll 8
  for (int kk = 0; kk < 128; ++kk) {
    const float4 w = W4[kk * 32];
    const float x0 = xl[ra][kk], x1 = xl[rb][kk];
    a0.x += x0*w.x; a0.y += x0*w.y; a0.z += x0*w.z; a0.w += x0*w.w;
    a1.x += x1*w.x; a1.y += x1*w.y; a1.z += x1*w.z; a1.w += x1*w.w;
  }
  const float4 bb = reinterpret_cast<const float4*>(bm[m])[jc];
  a0.x += bb.x; a0.y += bb.y; a0.z += bb.z; a0.w += bb.w;
  a1.x += bb.x; a1.y += bb.y; a1.z += bb.z; a1.w += bb.w;
  *reinterpret_cast<float4*>(om[m] + (size_t)(r0 + ra) * 128 + 4 * jc) = a0;
  *reinterpret_cast<float4*>(om[m] + (size_t)(r0 + rb) * 128 + 4 * jc) = a1;
}

// ---------------- edge multiplicity (verified round 1) -----------------------
__device__ __forceinline__ float cntf(int dnode, int s) {
  if (dnode == 256) return (s == 0 ? 1.f : 0.f) + (s == 255 ? 1.f : 0.f);
  float c = (s != dnode) ? 1.f : 0.f;          // semantic all-pairs (nodes 0..255)
  if (s == 0) c += 1.f;                        // query->segment
  if (s == dnode - 1) c += 2.f;                // qe chain + temporal h=1 fwd
  if (s == dnode + 1 && dnode <= 254) c += 1.f;// temporal h=1 bwd
  if (s == dnode - 2 && dnode >= 2) c += 1.f;  // temporal h=2 fwd
  if (s == dnode + 2 && dnode <= 253) c += 1.f;// temporal h=2 bwd
  return c;
}

// ---------------- k_attn2: fused dense attention (verified round 2) ----------
__global__ __launch_bounds__(256) void k_attn2(
    const float* __restrict__ q, const float* __restrict__ k,
    const float* __restrict__ v, const float* __restrict__ sk,
    const float* __restrict__ W_start, const float* __restrict__ b_start,
    const float* __restrict__ W_end, const float* __restrict__ b_end,
    float* __restrict__ out)
{
  __shared__ float P_l[128][66];
  __shared__ float den_l[2][16][8];
  __shared__ float comb[16][128];
  __shared__ float red[16][2][2];

  const int b = blockIdx.y;
  const int d0 = blockIdx.x * 16;
  const int tid = threadIdx.x;
  const int base = b * 257;

  const int wA = tid >> 6, lA = tid & 63;
  const int ddA = lA >> 2, hsA = lA & 3;
  const int hA = (wA & 1) * 4 + hsA;
  const int shA = wA >> 1;
  const int dnodeA = d0 + ddA + 1;
  const int jB = tid & 127, shB = tid >> 7, hB = jB >> 4;

  const float* qrow = q + (base + dnodeA) * 128 + hA * 16;
  const float4 qq0 = *(const float4*)(qrow + 0);
  const float4 qq1 = *(const float4*)(qrow + 4);
  const float4 qq2 = *(const float4*)(qrow + 8);
  const float4 qq3 = *(const float4*)(qrow + 12);

  float denr = 0.f;
  float accB[16];
  #pragma unroll
  for (int i = 0; i < 16; ++i) accB[i] = 0.f;

  for (int tile = 0; tile < 4; ++tile) {
    const int s0 = tile * 64;
    #pragma unroll 2
    for (int si = 0; si < 32; ++si) {
      const int s = shA * 32 + si;
      const float* krow = k + (base + s0 + s) * 128 + hA * 16;
      const float4 k0 = *(const float4*)(krow + 0);
      const float4 k1 = *(const float4*)(krow + 4);
      const float4 k2 = *(const float4*)(krow + 8);
      const float4 k3 = *(const float4*)(krow + 12);
      float dt = qq0.x*k0.x + qq0.y*k0.y + qq0.z*k0.z + qq0.w*k0.w
               + qq1.x*k1.x + qq1.y*k1.y + qq1.z*k1.z + qq1.w*k1.w
               + qq2.x*k2.x + qq2.y*k2.y + qq2.z*k2.z + qq2.w*k2.w
               + qq3.x*k3.x + qq3.y*k3.y + qq3.z*k3.z + qq3.w*k3.w;
      const float c = cntf(dnodeA, s0 + s);
      const float wv = c * __expf(dt * 0.25f);
      P_l[ddA * 8 + hA][s] = wv;
      denr += wv;
    }
    __syncthreads();
    for (int si2 = 0; si2 < 16; ++si2) {
      const int s = shB * 32 + si2 * 2;
      const float va = v[(base + s0 + s) * 128 + jB];
      const float vb = v[(base + s0 + s + 1) * 128 + jB];
      #pragma unroll
      for (int dd = 0; dd < 16; ++dd) {
        const float2 pw = *(const float2*)&P_l[dd * 8 + hB][s];
        accB[dd] += pw.x * va + pw.y * vb;
      }
    }
    __syncthreads();
  }

  den_l[shA][ddA][hA] = denr;
  __syncthreads();
  if (shB == 1) {
    #pragma unroll
    for (int dd = 0; dd < 16; ++dd) comb[dd][jB] = accB[dd];
  }
  __syncthreads();
  if (shB == 0) {
    const float wst = W_start[jB], wen = W_end[jB];
    #pragma unroll
    for (int dd = 0; dd < 16; ++dd) {
      const float den = den_l[0][dd][hB] + den_l[1][dd][hB];
      const float o = (accB[dd] + comb[dd][jB]) / (den + 1e-16f)
                    + sk[(base + d0 + dd + 1) * 128 + jB];
      float ps = o * wst, pe = o * wen;
      #pragma unroll
      for (int off = 1; off < 64; off <<= 1) {
        ps += __shfl_xor(ps, off);
        pe += __shfl_xor(pe, off);
      }
      if ((jB & 63) == 0) { red[dd][jB >> 6][0] = ps; red[dd][jB >> 6][1] = pe; }
    }
  }
  __syncthreads();
  if (tid < 16) {
    out[b * 256 + d0 + tid]        = red[tid][0][0] + red[tid][1][0] + b_start[0];
    out[2048 + b * 256 + d0 + tid] = red[tid][0][1] + red[tid][1][1] + b_end[0];
  }
}

extern "C" void kernel_launch(void* const* d_in, const int* in_sizes, int n_in,
                              void* d_out, int out_size, void* d_ws, size_t ws_size,
                              hipStream_t stream) {
  const int*   word_ids = (const int*)d_in[0];
  const int*   char_ids = (const int*)d_in[1];
  const float* video    = (const float*)d_in[2];
  const float* v_mask   = (const float*)d_in[3];
  const float* q_mask   = (const float*)d_in[4];
  const float* word_emb = (const float*)d_in[5];
  const float* char_emb = (const float*)d_in[6];
  const float* W_embed  = (const float*)d_in[7];
  const float* b_embed  = (const float*)d_in[8];
  const float* W_vproj  = (const float*)d_in[9];
  const float* b_vproj  = (const float*)d_in[10];
  const float* W_enc    = (const float*)d_in[11];
  const float* b_enc    = (const float*)d_in[12];
  const float* Wq       = (const float*)d_in[13];
  const float* bq       = (const float*)d_in[14];
  const float* Wk       = (const float*)d_in[15];
  const float* bk       = (const float*)d_in[16];
  const float* Wv       = (const float*)d_in[17];
  const float* bv       = (const float*)d_in[18];
  const float* Wskip    = (const float*)d_in[19];
  const float* bskip    = (const float*)d_in[20];
  const float* W_start  = (const float*)d_in[21];
  const float* b_start  = (const float*)d_in[22];
  const float* W_end    = (const float*)d_in[23];
  const float* b_end    = (const float*)d_in[24];

  float* xf   = (float*)d_ws;
  float* q    = xf + NN_ * DIM_;
  float* k    = q  + NN_ * DIM_;
  float* v    = k  + NN_ * DIM_;
  float* sk   = v  + NN_ * DIM_;
  float* part = sk + NN_ * DIM_;      // 8 * 2048 * 128 floats = 8 MB
  float* eq   = part + 8 * 2048 * 128; // 160 * 128 floats

  hipLaunchKernelGGL(kAQ, dim3(1184), dim3(256), 0, stream,
    video, W_vproj, word_ids, char_ids, word_emb, char_emb,
    W_embed, b_embed, W_enc, b_enc, q_mask, part, eq);
  hipLaunchKernelGGL(kBR, dim3(1032), dim3(256), 0, stream,
    part, b_vproj, W_enc, b_enc, v_mask, eq, xf);
  hipLaunchKernelGGL(kP, dim3(514), dim3(256), 0, stream,
    xf, Wq, bq, Wk, bk, Wv, bv, Wskip, bskip, q, k, v, sk);
  hipLaunchKernelGGL(k_attn2, dim3(16, 8), dim3(256), 0, stream,
    q, k, v, sk, W_start, b_start, W_end, b_end, (float*)d_out);
}

// Round 5
// 77.470 us; speedup vs baseline: 6.2114x; 1.4241x over previous
//
#include <hip/hip_runtime.h>
#include <hip/hip_bf16.h>
#include <math.h>

#define B_ 8
#define T_ 256
#define LQ_ 20
#define LC_ 10
#define DIM_ 128
#define N_ 257            // T+1
#define NN_ (B_*N_)       // 2056

// ---------------- kAQ: video @ W_vproj split-K  ∪  query per-(b,lq) rows -----
__global__ __launch_bounds__(256) void kAQ(
    const float* __restrict__ video, const float* __restrict__ Wv,
    const int* __restrict__ word_ids, const int* __restrict__ char_ids,
    const float* __restrict__ word_emb, const float* __restrict__ char_emb,
    const float* __restrict__ W_embed, const float* __restrict__ b_embed,
    const float* __restrict__ We, const float* __restrict__ be,
    const float* __restrict__ q_mask,
    float* __restrict__ part, float* __restrict__ eq)
{
  __shared__ float smem[16 * 128];
  const int blk = blockIdx.x, tid = threadIdx.x;
  if (blk < 1024) {
    float (*Vl)[128] = reinterpret_cast<float(*)[128]>(smem);
    const int rt = blk & 127, ks = blk >> 7;
    const int r0 = rt * 16;
    for (int idx4 = tid; idx4 < 512; idx4 += 256) {
      const int i = idx4 >> 5, f = idx4 & 31;
      reinterpret_cast<float4*>(&Vl[i][0])[f] =
        reinterpret_cast<const float4*>(video + (size_t)(r0 + i) * 1024 + ks * 128)[f];
    }
    __syncthreads();
    const int jc = tid & 31, rg = tid >> 5;
    const int ra = rg * 2, rb = ra + 1;
    const float4* W4 = reinterpret_cast<const float4*>(Wv + (size_t)ks * 128 * 128) + jc;
    float4 a0 = {0,0,0,0}, a1 = {0,0,0,0};
    #pragma unroll 8
    for (int k = 0; k < 128; ++k) {
      const float4 w = W4[k * 32];
      const float x0 = Vl[ra][k], x1 = Vl[rb][k];
      a0.x += x0*w.x; a0.y += x0*w.y; a0.z += x0*w.z; a0.w += x0*w.w;
      a1.x += x1*w.x; a1.y += x1*w.y; a1.z += x1*w.z; a1.w += x1*w.w;
    }
    *reinterpret_cast<float4*>(part + (((size_t)ks * 2048) + r0 + ra) * 128 + 4 * jc) = a0;
    *reinterpret_cast<float4*>(part + (((size_t)ks * 2048) + r0 + rb) * 128 + 4 * jc) = a1;
  } else {
    const int qi = blk - 1024;
    const int b = qi / 20, lq = qi - b * 20;
    float* emb = smem;            // [352]
    float* ps  = smem + 352;      // [2][128]
    float* hl  = smem + 608;      // [128]
    float* pe  = smem + 736;      // [2][128]
    const int wid = word_ids[b * LQ_ + lq];
    for (int m = tid; m < 300; m += 256) emb[m] = word_emb[(size_t)wid * 300 + m];
    if (tid < 50) {
      float s = 0.f;
      #pragma unroll
      for (int l = 0; l < 10; ++l) {
        const int cid = char_ids[(b * LQ_ + lq) * 10 + l];
        s += char_emb[cid * 50 + tid];
      }
      emb[300 + tid] = s * 0.1f;
    }
    __syncthreads();
    const int j = tid & 127, half = tid >> 7;
    float a = 0.f;
    const float* Wcol = W_embed + (size_t)(half * 175) * 128 + j;
    const float* eh = emb + half * 175;
    #pragma unroll 5
    for (int m = 0; m < 175; ++m) a += eh[m] * Wcol[(size_t)m * 128];
    ps[half * 128 + j] = a;
    __syncthreads();
    if (tid < 128) hl[tid] = ps[tid] + ps[128 + tid] + b_embed[tid];
    __syncthreads();
    float e = 0.f;
    #pragma unroll 8
    for (int kk = 0; kk < 64; ++kk)
      e += hl[half * 64 + kk] * We[(half * 64 + kk) * 128 + j];
    pe[half * 128 + j] = e;
    __syncthreads();
    if (tid < 128) {
      float ev = pe[tid] + pe[128 + tid] + be[tid];
      ev = fmaxf(ev, 0.f) * q_mask[b * LQ_ + lq];
      eq[(size_t)qi * 128 + tid] = ev;
    }
  }
}

// ---------------- kBR2: partial-reduce + enc + FUSED q/k/v/skip projections --
// blocks 0..1023: 2 video rows; blocks 1024..1031: query mean + node-0 proj
__global__ __launch_bounds__(256) void kBR2(
    const float* __restrict__ part, const float* __restrict__ bvp,
    const float* __restrict__ We, const float* __restrict__ be,
    const float* __restrict__ vmask, const float* __restrict__ eq,
    const float* __restrict__ Wq, const float* __restrict__ bq,
    const float* __restrict__ Wk, const float* __restrict__ bk,
    const float* __restrict__ Wvv, const float* __restrict__ bval,
    const float* __restrict__ Ws, const float* __restrict__ bs,
    float* __restrict__ xf, float* __restrict__ q, float* __restrict__ k,
    float* __restrict__ v, float* __restrict__ sk)
{
  __shared__ float h[2][128];
  __shared__ float ps[4][2][128];
  __shared__ float xe[2][128];
  const int blk = blockIdx.x, tid = threadIdx.x;
  const float* Wm[4] = {Wq, Wk, Wvv, Ws};
  const float* bm[4] = {bq, bk, bval, bs};
  float* om[4] = {q, k, v, sk};
  if (blk < 1024) {
    const int rloc = tid >> 7, col = tid & 127;
    const int row = 2 * blk + rloc;
    float s = bvp[col];
    #pragma unroll
    for (int ks = 0; ks < 8; ++ks) s += part[((size_t)ks * 2048 + row) * 128 + col];
    h[rloc][col] = s;
    __syncthreads();
    const int jc = tid & 31, rg = tid >> 5;
    const int r = rg & 1, ksub = rg >> 1;
    const float4* W4 = reinterpret_cast<const float4*>(We) + jc;
    float4 a = {0,0,0,0};
    #pragma unroll 8
    for (int kk = 0; kk < 32; ++kk) {
      const int kx = ksub * 32 + kk;
      const float4 w = W4[kx * 32];
      const float x = h[r][kx];
      a.x += x*w.x; a.y += x*w.y; a.z += x*w.z; a.w += x*w.w;
    }
    reinterpret_cast<float4*>(&ps[ksub][r][0])[jc] = a;
    __syncthreads();
    float e = be[col] + ps[0][rloc][col] + ps[1][rloc][col] + ps[2][rloc][col] + ps[3][rloc][col];
    e = fmaxf(e, 0.f) * vmask[row];
    const int bi = row >> 8, t = row & 255;
    const int node = bi * 257 + 1 + t;
    xf[(size_t)node * 128 + col] = e;
    xe[rloc][col] = e;
    __syncthreads();
    // fused projections for the 2 rows
    const int m = rg & 3, r2 = rg >> 2;
    const float4* W4p = reinterpret_cast<const float4*>(Wm[m]) + jc;
    float4 ac = reinterpret_cast<const float4*>(bm[m])[jc];
    #pragma unroll 8
    for (int kk = 0; kk < 128; ++kk) {
      const float4 w = W4p[kk * 32];
      const float x = xe[r2][kk];
      ac.x += x*w.x; ac.y += x*w.y; ac.z += x*w.z; ac.w += x*w.w;
    }
    const int row2 = 2 * blk + r2;
    const int node2 = (row2 >> 8) * 257 + 1 + (row2 & 255);
    *reinterpret_cast<float4*>(om[m] + (size_t)node2 * 128 + 4 * jc) = ac;
  } else {
    const int b = blk - 1024;
    if (tid < 128) {
      float s = 0.f;
      #pragma unroll 4
      for (int lq = 0; lq < LQ_; ++lq) s += eq[((size_t)b * LQ_ + lq) * 128 + tid];
      const float qv = s * (1.f / LQ_);
      xf[((size_t)b * 257) * 128 + tid] = qv;
      xe[0][tid] = qv;
    }
    __syncthreads();
    if (tid < 128) {
      const int jc = tid & 31, m = tid >> 5;
      const float4* W4p = reinterpret_cast<const float4*>(Wm[m]) + jc;
      float4 ac = reinterpret_cast<const float4*>(bm[m])[jc];
      #pragma unroll 8
      for (int kk = 0; kk < 128; ++kk) {
        const float4 w = W4p[kk * 32];
        const float x = xe[0][kk];
        ac.x += x*w.x; ac.y += x*w.y; ac.z += x*w.z; ac.w += x*w.w;
      }
      *reinterpret_cast<float4*>(om[m] + ((size_t)b * 257) * 128 + 4 * jc) = ac;
    }
  }
}

// ---------------- edge multiplicity (verified round 1) -----------------------
__device__ __forceinline__ float cntf(int dnode, int s) {
  if (dnode == 256) return (s == 0 ? 1.f : 0.f) + (s == 255 ? 1.f : 0.f);
  float c = (s != dnode) ? 1.f : 0.f;          // semantic all-pairs (nodes 0..255)
  if (s == 0) c += 1.f;                        // query->segment
  if (s == dnode - 1) c += 2.f;                // qe chain + temporal h=1 fwd
  if (s == dnode + 1 && dnode <= 254) c += 1.f;// temporal h=1 bwd
  if (s == dnode - 2 && dnode >= 2) c += 1.f;  // temporal h=2 fwd
  if (s == dnode + 2 && dnode <= 253) c += 1.f;// temporal h=2 bwd
  return c;
}

// ---------------- k_attn3: s-split attention partials ------------------------
// grid (16 dtiles, 4 stiles, 8 b), 256 thr. K-tile staged in LDS.
__global__ __launch_bounds__(256) void k_attn3(
    const float* __restrict__ q, const float* __restrict__ k,
    const float* __restrict__ v,
    float* __restrict__ npart, float* __restrict__ dpart)
{
  __shared__ float Kl[64][128];      // 32 KB K tile; aliased as comb after phase A
  __shared__ float P_l[128][66];
  __shared__ float den_l[2][16][8];
  const int d0 = blockIdx.x * 16;
  const int y  = blockIdx.y;
  const int b  = blockIdx.z;
  const int tid = threadIdx.x;
  const int base = b * 257;
  const int s0 = y * 64;

  {
    const float4* src = reinterpret_cast<const float4*>(k + (size_t)(base + s0) * 128);
    float4* dst = reinterpret_cast<float4*>(Kl);
    #pragma unroll
    for (int i = 0; i < 8; ++i) dst[tid + i * 256] = src[tid + i * 256];
  }

  const int wA = tid >> 6, lA = tid & 63;
  const int ddA = lA >> 2, hsA = lA & 3;
  const int hA = (wA & 1) * 4 + hsA;
  const int shA = wA >> 1;
  const int dnodeA = d0 + ddA + 1;
  const int jB = tid & 127, shB = tid >> 7, hB = jB >> 4;

  const float* qrow = q + (size_t)(base + dnodeA) * 128 + hA * 16;
  const float4 qq0 = *(const float4*)(qrow + 0);
  const float4 qq1 = *(const float4*)(qrow + 4);
  const float4 qq2 = *(const float4*)(qrow + 8);
  const float4 qq3 = *(const float4*)(qrow + 12);

  __syncthreads();   // K staged

  float denr = 0.f;
  #pragma unroll 2
  for (int si = 0; si < 32; ++si) {
    const int s = shA * 32 + si;
    const float* krow = &Kl[s][hA * 16];
    const float4 k0 = *(const float4*)(krow + 0);
    const float4 k1 = *(const float4*)(krow + 4);
    const float4 k2 = *(const float4*)(krow + 8);
    const float4 k3 = *(const float4*)(krow + 12);
    float dt = qq0.x*k0.x + qq0.y*k0.y + qq0.z*k0.z + qq0.w*k0.w
             + qq1.x*k1.x + qq1.y*k1.y + qq1.z*k1.z + qq1.w*k1.w
             + qq2.x*k2.x + qq2.y*k2.y + qq2.z*k2.z + qq2.w*k2.w
             + qq3.x*k3.x + qq3.y*k3.y + qq3.z*k3.z + qq3.w*k3.w;
    const float c = cntf(dnodeA, s0 + s);
    const float wv = c * __expf(dt * 0.25f);
    P_l[ddA * 8 + hA][s] = wv;
    denr += wv;
  }
  den_l[shA][ddA][hA] = denr;
  __syncthreads();

  float accB[16];
  #pragma unroll
  for (int i = 0; i < 16; ++i) accB[i] = 0.f;
  for (int si2 = 0; si2 < 16; ++si2) {
    const int s = shB * 32 + si2 * 2;
    const float va = v[(size_t)(base + s0 + s) * 128 + jB];
    const float vb = v[(size_t)(base + s0 + s + 1) * 128 + jB];
    #pragma unroll
    for (int dd = 0; dd < 16; ++dd) {
      const float2 pw = *(const float2*)&P_l[dd * 8 + hB][s];
      accB[dd] += pw.x * va + pw.y * vb;
    }
  }
  __syncthreads();               // Kl no longer read; safe to alias
  float* comb = &Kl[0][0];
  if (shB == 1) {
    #pragma unroll
    for (int dd = 0; dd < 16; ++dd) comb[dd * 128 + jB] = accB[dd];
  }
  __syncthreads();
  const size_t pb = ((size_t)y * 8 + b) * 256 + d0;
  if (shB == 0) {
    #pragma unroll
    for (int dd = 0; dd < 16; ++dd)
      npart[(pb + dd) * 128 + jB] = accB[dd] + comb[dd * 128 + jB];
  }
  if (tid < 128) {
    const int dd = tid >> 3, hh = tid & 7;
    dpart[(pb + dd) * 8 + hh] = den_l[0][dd][hh] + den_l[1][dd][hh];
  }
}

// ---------------- k_red: combine partials + skip + start/end logits ----------
__global__ __launch_bounds__(256) void k_red(
    const float* __restrict__ npart, const float* __restrict__ dpart,
    const float* __restrict__ sk,
    const float* __restrict__ W_start, const float* __restrict__ b_start,
    const float* __restrict__ W_end, const float* __restrict__ b_end,
    float* __restrict__ out)
{
  __shared__ float red[16][2][2];
  const int d0 = blockIdx.x * 16;
  const int b = blockIdx.y;
  const int tid = threadIdx.x;
  const int base = b * 257;
  const int jB = tid & 127, shB = tid >> 7;
  const int hB = jB >> 4;
  const float wst = W_start[jB], wen = W_end[jB];
  #pragma unroll
  for (int dd8 = 0; dd8 < 8; ++dd8) {
    const int dd = shB * 8 + dd8;
    const int dst = d0 + dd;
    float num = 0.f, den = 0.f;
    #pragma unroll
    for (int y = 0; y < 4; ++y) {
      const size_t pb = ((size_t)y * 8 + b) * 256 + dst;
      num += npart[pb * 128 + jB];
      den += dpart[pb * 8 + hB];
    }
    const float o = num / (den + 1e-16f) + sk[(size_t)(base + dst + 1) * 128 + jB];
    float psum = o * wst, pesum = o * wen;
    #pragma unroll
    for (int off = 1; off < 64; off <<= 1) {
      psum += __shfl_xor(psum, off);
      pesum += __shfl_xor(pesum, off);
    }
    if ((tid & 63) == 0) { red[dd][jB >> 6][0] = psum; red[dd][jB >> 6][1] = pesum; }
  }
  __syncthreads();
  if (tid < 16) {
    out[b * 256 + d0 + tid]        = red[tid][0][0] + red[tid][1][0] + b_start[0];
    out[2048 + b * 256 + d0 + tid] = red[tid][0][1] + red[tid][1][1] + b_end[0];
  }
}

extern "C" void kernel_launch(void* const* d_in, const int* in_sizes, int n_in,
                              void* d_out, int out_size, void* d_ws, size_t ws_size,
                              hipStream_t stream) {
  const int*   word_ids = (const int*)d_in[0];
  const int*   char_ids = (const int*)d_in[1];
  const float* video    = (const float*)d_in[2];
  const float* v_mask   = (const float*)d_in[3];
  const float* q_mask   = (const float*)d_in[4];
  const float* word_emb = (const float*)d_in[5];
  const float* char_emb = (const float*)d_in[6];
  const float* W_embed  = (const float*)d_in[7];
  const float* b_embed  = (const float*)d_in[8];
  const float* W_vproj  = (const float*)d_in[9];
  const float* b_vproj  = (const float*)d_in[10];
  const float* W_enc    = (const float*)d_in[11];
  const float* b_enc    = (const float*)d_in[12];
  const float* Wq       = (const float*)d_in[13];
  const float* bq       = (const float*)d_in[14];
  const float* Wk       = (const float*)d_in[15];
  const float* bk       = (const float*)d_in[16];
  const float* Wv       = (const float*)d_in[17];
  const float* bv       = (const float*)d_in[18];
  const float* Wskip    = (const float*)d_in[19];
  const float* bskip    = (const float*)d_in[20];
  const float* W_start  = (const float*)d_in[21];
  const float* b_start  = (const float*)d_in[22];
  const float* W_end    = (const float*)d_in[23];
  const float* b_end    = (const float*)d_in[24];

  float* xf   = (float*)d_ws;
  float* q    = xf + NN_ * DIM_;
  float* k    = q  + NN_ * DIM_;
  float* v    = k  + NN_ * DIM_;
  float* sk   = v  + NN_ * DIM_;
  float* part = sk + NN_ * DIM_;        // 8 * 2048 * 128 floats = 8 MB
  float* eq   = part + 8 * 2048 * 128;  // 160 * 128 floats
  float* npart = part;                  // alias: part dead after kBR2
  float* dpart = npart + (size_t)32 * 256 * 128;

  hipLaunchKernelGGL(kAQ, dim3(1184), dim3(256), 0, stream,
    video, W_vproj, word_ids, char_ids, word_emb, char_emb,
    W_embed, b_embed, W_enc, b_enc, q_mask, part, eq);
  hipLaunchKernelGGL(kBR2, dim3(1032), dim3(256), 0, stream,
    part, b_vproj, W_enc, b_enc, v_mask, eq,
    Wq, bq, Wk, bk, Wv, bv, Wskip, bskip, xf, q, k, v, sk);
  hipLaunchKernelGGL(k_attn3, dim3(16, 4, 8), dim3(256), 0, stream,
    q, k, v, npart, dpart);
  hipLaunchKernelGGL(k_red, dim3(16, 8), dim3(256), 0, stream,
    npart, dpart, sk, W_start, b_start, W_end, b_end, (float*)d_out);
}